// Round 4
// baseline (13055.196 us; speedup 1.0000x reference)
//
#include <hip/hip_runtime.h>
#include <hip/hip_fp16.h>

#define RES 512
#define NF 32

static __device__ __forceinline__ float h2f(float v) {
    return __half2float(__float2half(v));
}

// One thread per point. Single gather pass; merged per-axis derivative
// accumulators D0/D1/D2 (plane0:(x->D0,y->D1), plane1:(x->D0,z->D2),
// plane2:(y->D1,z->D2)). Forward h and the fp16 MLP pre-activations are
// computed with numpy-exact semantics (no fma/contract, exact op order and
// associativity, fp16 rounding) so every leaky-ReLU sign decision matches
// the reference bitwise. Backward (m,g,D,nabla) stays fp32 (value-level,
// well under the 2% threshold).
__global__ __launch_bounds__(256) void stylesdf_fused(
    const float* __restrict__ x,
    const float* __restrict__ planes,
    const float* __restrict__ W1,
    const float* __restrict__ b1,
    const float* __restrict__ W2,
    const float* __restrict__ b2,
    float* __restrict__ out, int N)
{
#pragma clang fp contract(off)
    __shared__ __align__(16) float sW1[NF * NF];   // fp16-valued W1*s, row-major [i][j]
    __shared__ __align__(16) float sW1T[NF * NF];  // transposed [j][i]
    __shared__ __align__(16) float sW2[NF * 4];    // fp16-valued W2*s
    __shared__ __align__(16) float sB1[NF];
    __shared__ __align__(16) float sB2[4];
    __shared__ __align__(16) float sW2c0[NF];

    const float S16 = h2f(0.17677669529663687f);  // fp16(1/sqrt(32))
    const float LREL = h2f(0.2f);                 // fp16(0.2) = 0.199951171875

    const int tid = threadIdx.x;
    for (int idx = tid; idx < NF * NF; idx += 256) {
        float w = h2f(h2f(W1[idx]) * S16);  // fp16 multiply semantics
        sW1[idx] = w;
        sW1T[(idx & 31) * NF + (idx >> 5)] = w;
    }
    if (tid < NF * 4) sW2[tid] = h2f(h2f(W2[tid]) * S16);
    if (tid < NF) { sB1[tid] = h2f(b1[tid]); sW2c0[tid] = h2f(h2f(W2[tid * 4]) * S16); }
    if (tid < 4) sB2[tid] = h2f(b2[tid]);
    __syncthreads();

    const int p = blockIdx.x * 256 + tid;
    if (p >= N) return;

    float fr[3];
    int i0[3], i1[3];
#pragma unroll
    for (int c = 0; c < 3; ++c) {
        float xt = (x[3 * p + c] + 1.0f) * 0.5f;
        float pos = xt * 511.0f;
        float pf = floorf(pos);
        fr[c] = pos - pf;
        int q = (int)pf;
        q = q < 0 ? 0 : (q > 511 ? 511 : q);
        i0[c] = q;
        i1[c] = (q + 1 > 511) ? 511 : q + 1;
    }

    float h[NF], D0[NF], D1[NF], D2[NF];
#pragma unroll
    for (int f = 0; f < NF; ++f) { h[f] = 0.f; D0[f] = 0.f; D1[f] = 0.f; D2[f] = 0.f; }

    // Gather. h follows the reference bitwise:
    //   t4 = (v00*(1-fb) + v01*fb) * (1-fa)
    //   t8 = (v10*(1-fb) + v11*fb) * fa
    //   h  = (h + t4) + t8          <-- two separate adds, left-to-right
#define PLANE_GATHER(PLIDX, A, B, DA, DB)                                            \
    {                                                                                \
        const float fa = fr[A], fb = fr[B];                                          \
        const float ifa = 1.0f - fa, ifb = 1.0f - fb;                                \
        const float* pl = planes + (PLIDX) * (RES * RES * NF);                       \
        const float4* r00 = (const float4*)(pl + ((i0[A] * RES + i0[B]) << 5));      \
        const float4* r01 = (const float4*)(pl + ((i0[A] * RES + i1[B]) << 5));      \
        const float4* r10 = (const float4*)(pl + ((i1[A] * RES + i0[B]) << 5));      \
        const float4* r11 = (const float4*)(pl + ((i1[A] * RES + i1[B]) << 5));      \
        _Pragma("unroll")                                                            \
        for (int q = 0; q < 8; ++q) {                                                \
            float4 v00 = r00[q], v01 = r01[q], v10 = r10[q], v11 = r11[q];           \
            const float* a00 = (const float*)&v00;                                   \
            const float* a01 = (const float*)&v01;                                   \
            const float* a10 = (const float*)&v10;                                   \
            const float* a11 = (const float*)&v11;                                   \
            _Pragma("unroll")                                                        \
            for (int c = 0; c < 4; ++c) {                                            \
                const int f = 4 * q + c;                                             \
                float t4 = (a00[c] * ifb + a01[c] * fb) * ifa;                       \
                float t8 = (a10[c] * ifb + a11[c] * fb) * fa;                        \
                float hs = h[f] + t4;                                                \
                h[f] = hs + t8;                                                      \
                DA[f] += (a10[c] - a00[c]) * ifb + (a11[c] - a01[c]) * fb;           \
                DB[f] += (a01[c] - a00[c]) * ifa + (a11[c] - a10[c]) * fa;           \
            }                                                                        \
        }                                                                            \
    }

    PLANE_GATHER(0, 0, 1, D0, D1)
    PLANE_GATHER(1, 0, 2, D0, D2)
    PLANE_GATHER(2, 1, 2, D1, D2)
#undef PLANE_GATHER

    // ---- store h (fp32, bitwise-matching np order), then round in place ----
    {
        float4* ho = (float4*)(out + (size_t)N + (size_t)p * NF);
#pragma unroll
        for (int q = 0; q < 8; ++q)
            ho[q] = make_float4(h[4 * q], h[4 * q + 1], h[4 * q + 2], h[4 * q + 3]);
    }
#pragma unroll
    for (int f = 0; f < NF; ++f) h[f] = h2f(h[f]);  // h16, fp16-valued

    // ---- y = h16 @ W1s : sequential fp32 accumulation over i (numpy half dot) ----
    float y[NF];
#pragma unroll
    for (int j = 0; j < NF; ++j) y[j] = 0.f;
#pragma unroll
    for (int i = 0; i < NF; ++i) {
        const float hi = h[i];
        const float4* row = (const float4*)(sW1 + i * NF);
#pragma unroll
        for (int q = 0; q < 8; ++q) {
            float4 w = row[q];
            y[4 * q + 0] = y[4 * q + 0] + hi * w.x;  // contract off: round mul, round add
            y[4 * q + 1] = y[4 * q + 1] + hi * w.y;
            y[4 * q + 2] = y[4 * q + 2] + hi * w.z;
            y[4 * q + 3] = y[4 * q + 3] + hi * w.w;
        }
    }

    // ---- per-j: fp16 round, bias, leaky, layer-2 acc, m_j, g accumulation ----
    float o0 = 0.f, o1 = 0.f, o2 = 0.f, o3 = 0.f;
    float g[NF];
#pragma unroll
    for (int i = 0; i < NF; ++i) g[i] = 0.f;
#pragma unroll
    for (int j = 0; j < NF; ++j) {
        const float yd = h2f(y[j]);            // fp16 dot result
        const float y16 = h2f(yd + sB1[j]);    // fp16 bias add
        const bool nn = y16 >= 0.0f;
        const float zj = nn ? y16 : h2f(LREL * y16);  // fp16 leaky value
        const float4 w2 = ((const float4*)sW2)[j];
        o0 = o0 + zj * w2.x;  // sequential fp32 accumulation over j
        o1 = o1 + zj * w2.y;
        o2 = o2 + zj * w2.z;
        o3 = o3 + zj * w2.w;
        const float mj = (nn ? 1.0f : LREL) * sW2c0[j];
        const float4* rowT = (const float4*)(sW1T + j * NF);
#pragma unroll
        for (int q = 0; q < 8; ++q) {
            float4 w = rowT[q];
            g[4 * q + 0] = fmaf(mj, w.x, g[4 * q + 0]);
            g[4 * q + 1] = fmaf(mj, w.y, g[4 * q + 1]);
            g[4 * q + 2] = fmaf(mj, w.z, g[4 * q + 2]);
            g[4 * q + 3] = fmaf(mj, w.w, g[4 * q + 3]);
        }
    }
    // fp16 rounding of layer-2 output + bias (sdf/rgb pre-activations)
    o0 = h2f(h2f(o0) + sB2[0]);
    o1 = h2f(h2f(o1) + sB2[1]);
    o2 = h2f(h2f(o2) + sB2[2]);
    o3 = h2f(h2f(o3) + sB2[3]);

    // ---- nablas = 511 * dot(g, D_axis) ----
    float n0 = 0.f, n1 = 0.f, n2 = 0.f;
#pragma unroll
    for (int i = 0; i < NF; ++i) {
        n0 = fmaf(g[i], D0[i], n0);
        n1 = fmaf(g[i], D1[i], n1);
        n2 = fmaf(g[i], D2[i], n2);
    }
    n0 *= 511.0f; n1 *= 511.0f; n2 *= 511.0f;

    const float r0 = (tanhf(o1) + 1.0f) * 0.5f;
    const float r1 = (tanhf(o2) + 1.0f) * 0.5f;
    const float r2 = (tanhf(o3) + 1.0f) * 0.5f;

    // ---- stores ----
    out[p] = o0;  // sdf
    {
        const size_t nb = (size_t)N * 33 + (size_t)p * 3;
        out[nb + 0] = n0; out[nb + 1] = n1; out[nb + 2] = n2;
        const size_t rb = (size_t)N * 36 + (size_t)p * 3;
        out[rb + 0] = r0; out[rb + 1] = r1; out[rb + 2] = r2;
    }
}

extern "C" void kernel_launch(void* const* d_in, const int* in_sizes, int n_in,
                              void* d_out, int out_size, void* d_ws, size_t ws_size,
                              hipStream_t stream) {
    const float* x      = (const float*)d_in[0];
    const float* planes = (const float*)d_in[1];
    const float* W1     = (const float*)d_in[2];
    const float* b1     = (const float*)d_in[3];
    const float* W2     = (const float*)d_in[4];
    const float* b2     = (const float*)d_in[5];
    float* out = (float*)d_out;
    const int N = in_sizes[0] / 3;
    const int blocks = (N + 255) / 256;
    stylesdf_fused<<<blocks, 256, 0, stream>>>(x, planes, W1, b1, W2, b2, out, N);
}